// Round 10
// baseline (3426.162 us; speedup 1.0000x reference)
//
#include <hip/hip_runtime.h>

#define N_NODES 100000
#define N_EDGES 3200000
#define N_IN    128
#define N_OUT   64
#define ITERS   150
#define LEAK    0.01f

#define NBLK    256            // 1 block per CU
#define NT      960            // 15 waves
#define GROUPS  240            // NT/4 quads
#define RPB     391            // ceil(100000/256) rows per block
#define SCAN_CHUNK 1024
#define SCAN_NBLK  98          // 98*1024 >= N_NODES+1
#define ARRSTR  16             // ints between arrival slots (64B)
#define CRS     16             // ints between conv-ring slots (64B)
#define YSTR    100096         // y buffer stride (float4-aligned)
#define NBUF    150
#define CSRMAX  (N_EDGES + 8 * N_NODES)   // padded CSR upper bound (4.0M)

__device__ __forceinline__ float mml(float v) {
    v = (v < 0.0f) ? v * LEAK : v;
    if (v > 0.5f) v = 1.0f - 0.25f / v;
    return v;
}

__global__ void k_binit(const float* __restrict__ biases, float* __restrict__ b_in) {
    int i = blockIdx.x * blockDim.x + threadIdx.x;
    if (i < N_NODES) b_in[i] = biases[i];
}

// node_in.at[in_indices].set(in_w * x) -> last-write-wins for duplicates
__global__ void k_scatter_in(const float* __restrict__ x,
                             const float* __restrict__ in_w,
                             const int*   __restrict__ in_idx,
                             const float* __restrict__ biases,
                             float* __restrict__ b_in) {
    int k = threadIdx.x;
    if (k < N_IN) {
        int idx = in_idx[k];
        bool last = true;
        for (int j = k + 1; j < N_IN; ++j)
            if (in_idx[j] == idx) { last = false; break; }
        if (last) b_in[idx] = biases[idx] + in_w[k] * x[k];
    }
}

// y^(1) = act(0 + b_in)
__global__ void k_y0(const float* __restrict__ b_in, float* __restrict__ y0) {
    int i = blockIdx.x * blockDim.x + threadIdx.x;
    if (i < N_NODES) y0[i] = mml(b_in[i]);
}

// plain row histogram
__global__ void k_hist(const int* __restrict__ rows, int* __restrict__ counts) {
    int i = blockIdx.x * blockDim.x + threadIdx.x;
    int stride = gridDim.x * blockDim.x;
    for (; i < N_EDGES; i += stride) atomicAdd(&counts[rows[i]], 1);
}

// scan over row lengths PADDED to multiple of 8 (uniform per-lane batches)
__global__ void k_scan1(const int* __restrict__ counts, int* __restrict__ rp,
                        int* __restrict__ blockSums) {
    __shared__ int sm[SCAN_CHUNK];
    int t = threadIdx.x;
    int i = blockIdx.x * SCAN_CHUNK + t;
    int v = (i < N_NODES) ? ((counts[i] + 7) & ~7) : 0;
    sm[t] = v;
    __syncthreads();
    for (int off = 1; off < SCAN_CHUNK; off <<= 1) {
        int add = (t >= off) ? sm[t - off] : 0;
        __syncthreads();
        sm[t] += add;
        __syncthreads();
    }
    if (i <= N_NODES) rp[i] = sm[t] - v;
    if (t == SCAN_CHUNK - 1) blockSums[blockIdx.x] = sm[t];
}

__global__ void k_scan2(int* __restrict__ blockSums) {
    __shared__ int sm[128];
    int t = threadIdx.x;
    int v = (t < SCAN_NBLK) ? blockSums[t] : 0;
    sm[t] = v;
    __syncthreads();
    for (int off = 1; off < 128; off <<= 1) {
        int add = (t >= off) ? sm[t - off] : 0;
        __syncthreads();
        sm[t] += add;
        __syncthreads();
    }
    if (t < SCAN_NBLK) blockSums[t] = sm[t] - v;
}

__global__ void k_scan3(int* __restrict__ rp, const int* __restrict__ blockSums,
                        int* __restrict__ next) {
    int i = blockIdx.x * SCAN_CHUNK + threadIdx.x;
    if (i <= N_NODES) {
        int val = rp[i] + blockSums[blockIdx.x];
        rp[i] = val;
        if (i < N_NODES) next[i] = val;
    }
}

// CSR fill: real edges at row front; padding slots stay (0, 0.0f) from memset
__global__ void k_scatter_edges(const int* __restrict__ rows, const int* __restrict__ cols,
                                const float* __restrict__ w,
                                int* __restrict__ next, int2* __restrict__ csr) {
    int i = blockIdx.x * blockDim.x + threadIdx.x;
    int stride = gridDim.x * blockDim.x;
    for (; i < N_EDGES; i += stride) {
        int r = rows[i];
        int p = atomicAdd(&next[r], 1);
        csr[p] = make_int2(cols[i], __float_as_int(w[i]));
    }
}

// Flat persistent loop, explicit-MLP gather phase + period-2 early exit.
template <bool SC1>
__global__ __launch_bounds__(NT) void k_iterate(
    const int*  __restrict__ rp,
    const int2* __restrict__ csr,
    const float* __restrict__ b_in,
    float* __restrict__ ybufs,
    int* __restrict__ arr,
    int* __restrict__ convring,
    const int* __restrict__ out_idx,
    const float* __restrict__ out_w,
    float* __restrict__ out,
    int nbuf)
{
    const int b = blockIdx.x, t = threadIdx.x;
    const int gq = t >> 2, j = t & 3;
    const int row0 = b * RPB;
    const int row_end = (row0 + RPB < N_NODES) ? row0 + RPB : N_NODES;
    const int nrows = row_end - row0;
    const int r1 = row0 + gq, r2 = row0 + gq + GROUPS;
    const bool h1 = (gq < nrows), h2 = (gq + GROUPS < nrows);

    // iteration-invariant per-thread row state (registers); padded rows ->
    // every lane of a quad runs exactly n batches of 2 edges (stride 8)
    int beg1 = 0, n1 = 0, beg2 = 0, n2 = 0;
    float bi1 = 0.f, bi2 = 0.f;
    if (h1) { int s = rp[r1]; n1 = (rp[r1 + 1] - s) >> 3; beg1 = s + j; bi1 = b_in[r1]; }
    if (h2) { int s = rp[r2]; n2 = (rp[r2 + 1] - s) >> 3; beg2 = s + j; bi2 = b_in[r2]; }
    const int nmax = (n1 > n2) ? n1 : n2;

    int finalbuf = (ITERS - 1) % nbuf;
    for (int it = 1; it <= ITERS - 1; ++it) {
        const float* ysrc = ybufs + (size_t)((it - 1) % nbuf) * YSTR;
        float*       ydst = ybufs + (size_t)(it % nbuf) * YSTR;
        const float* yp2  = ybufs + (size_t)((it >= 3 ? it - 2 : 0) % nbuf) * YSTR;

        // ---- gather phase: r1/r2 interleaved, 4 CSR loads -> 4 gathers -> 4 fma
        float acc1 = 0.f, acc2 = 0.f;
        int e1 = beg1, e2 = beg2;
        for (int k = 0; k < nmax; ++k) {
            int2 a0, a1, c0, c1;
            const bool p = (k < n1), q = (k < n2);
            if (p) { a0 = csr[e1]; a1 = csr[e1 + 4]; }
            if (q) { c0 = csr[e2]; c1 = csr[e2 + 4]; }
            float ya0, ya1, yc0, yc1;
            if (p) {
                if (SC1) {
                    ya0 = __hip_atomic_load(&ysrc[a0.x], __ATOMIC_RELAXED, __HIP_MEMORY_SCOPE_AGENT);
                    ya1 = __hip_atomic_load(&ysrc[a1.x], __ATOMIC_RELAXED, __HIP_MEMORY_SCOPE_AGENT);
                } else { ya0 = ysrc[a0.x]; ya1 = ysrc[a1.x]; }
            }
            if (q) {
                if (SC1) {
                    yc0 = __hip_atomic_load(&ysrc[c0.x], __ATOMIC_RELAXED, __HIP_MEMORY_SCOPE_AGENT);
                    yc1 = __hip_atomic_load(&ysrc[c1.x], __ATOMIC_RELAXED, __HIP_MEMORY_SCOPE_AGENT);
                } else { yc0 = ysrc[c0.x]; yc1 = ysrc[c1.x]; }
            }
            if (p) {
                acc1 = fmaf(__int_as_float(a0.y), ya0, acc1);
                acc1 = fmaf(__int_as_float(a1.y), ya1, acc1);
                e1 += 8;
            }
            if (q) {
                acc2 = fmaf(__int_as_float(c0.y), yc0, acc2);
                acc2 = fmaf(__int_as_float(c1.y), yc1, acc2);
                e2 += 8;
            }
        }

        // ---- finalize + period-2 detection (y^(it) ?= y^(it-2), bitwise)
        acc1 += __shfl_xor(acc1, 1); acc1 += __shfl_xor(acc1, 2);
        acc2 += __shfl_xor(acc2, 1); acc2 += __shfl_xor(acc2, 2);
        int convflag = (!SC1 && it >= 3) ? 1 : 0;
        if (j == 0) {
            if (h1) {
                float v = mml(bi1 + acc1);
                __hip_atomic_store(&ydst[r1], v, __ATOMIC_RELAXED, __HIP_MEMORY_SCOPE_AGENT);
                if (convflag) convflag = (__float_as_int(v) == __float_as_int(yp2[r1]));
            }
            if (h2) {
                float v = mml(bi2 + acc2);
                __hip_atomic_store(&ydst[r2], v, __ATOMIC_RELAXED, __HIP_MEMORY_SCOPE_AGENT);
                if (convflag) convflag = convflag && (__float_as_int(v) == __float_as_int(yp2[r2]));
            }
        }
        asm volatile("s_waitcnt vmcnt(0)" ::: "memory");   // y stores ack'd at MALL
        int blockconv = __syncthreads_and(j != 0 || convflag);

        // ---- signal: conv ring slot first, then (ordered) arrival
        if (t == 0) {
            __hip_atomic_store(&convring[((it & 3) * NBLK + b) * CRS], blockconv,
                               __ATOMIC_RELAXED, __HIP_MEMORY_SCOPE_AGENT);
            asm volatile("s_waitcnt vmcnt(0)" ::: "memory");  // ring visible before arr
            __hip_atomic_store(&arr[b * ARRSTR], it,
                               __ATOMIC_RELAXED, __HIP_MEMORY_SCOPE_AGENT);
        }
        // ---- rendezvous: thread t polls only slot t (monotonic)
        int cb = 1;
        if (t < NBLK) {
            while (__hip_atomic_load(&arr[t * ARRSTR], __ATOMIC_RELAXED,
                                     __HIP_MEMORY_SCOPE_AGENT) < it)
                __builtin_amdgcn_s_sleep(1);
            cb = __hip_atomic_load(&convring[((it & 3) * NBLK + t) * CRS],
                                   __ATOMIC_RELAXED, __HIP_MEMORY_SCOPE_AGENT);
        }
        int allconv = __syncthreads_and(cb != 0);
        if (allconv) {
            // exact period-2 cycle: y^(149) = parity-matched buffer
            finalbuf = (((ITERS - 1 - it) & 1) == 0) ? (it % nbuf) : ((it - 1) % nbuf);
            break;
        }
    }

    if (b == 0 && t < N_OUT) {
        const float* yfin = ybufs + (size_t)finalbuf * YSTR;
        out[t] = out_w[t] * __hip_atomic_load(&yfin[out_idx[t]],
                   __ATOMIC_RELAXED, __HIP_MEMORY_SCOPE_AGENT);
    }
}

extern "C" void kernel_launch(void* const* d_in, const int* in_sizes, int n_in,
                              void* d_out, int out_size, void* d_ws, size_t ws_size,
                              hipStream_t stream) {
    const float* x      = (const float*)d_in[0];
    const float* in_w   = (const float*)d_in[1];
    const float* rec_w  = (const float*)d_in[2];
    const float* biases = (const float*)d_in[3];
    const float* out_w  = (const float*)d_in[4];
    const int*   in_idx = (const int*)d_in[5];
    const int*   e_rows = (const int*)d_in[6];
    const int*   e_cols = (const int*)d_in[7];
    const int*   out_idx= (const int*)d_in[8];
    float* out = (float*)d_out;

    char* ws = (char*)d_ws;
    float* b_in    = (float*)ws;                       // 100000 f
    int*   rp      = (int*)(b_in + N_NODES);           // 100001 (+pad)
    int*   counts  = rp + (N_NODES + 64);              // 100000 (also `next`)
    int*   blockSums = counts + N_NODES;               // 128
    int*   arr     = blockSums + 128;                  // NBLK*ARRSTR
    int*   convring= arr + NBLK * ARRSTR;              // 4*NBLK*CRS
    size_t off = (size_t)((char*)(convring + 4 * NBLK * CRS) - ws);
    off = (off + 255) & ~(size_t)255;
    int2* csr = (int2*)(ws + off);                     // padded CSR, <= 32 MB
    size_t off2 = off + (size_t)CSRMAX * sizeof(int2);
    off2 = (off2 + 255) & ~(size_t)255;
    float* ybufs = (float*)(ws + off2);

    long long avail = ((long long)ws_size - (long long)off2) /
                      (long long)(YSTR * sizeof(float));
    int nbuf, sc1mode;
    if (avail >= 48) {                 // enough rotation for de-facto-certain eviction
        nbuf = (avail >= NBUF) ? NBUF : (int)avail;
        sc1mode = 0;
    } else { nbuf = 2; sc1mode = 1; }  // L2-bypassing gathers, always correct

    hipMemsetAsync(counts, 0, N_NODES * sizeof(int), stream);
    hipMemsetAsync(arr, 0, (NBLK * ARRSTR + 4 * NBLK * CRS) * sizeof(int), stream);
    hipMemsetAsync(csr, 0, (size_t)CSRMAX * sizeof(int2), stream);  // padding = (0, 0.0f)

    k_binit<<<391, 256, 0, stream>>>(biases, b_in);
    k_scatter_in<<<1, 128, 0, stream>>>(x, in_w, in_idx, biases, b_in);
    k_y0<<<391, 256, 0, stream>>>(b_in, ybufs);        // buffer 0 = y^(1)

    k_hist<<<1024, 256, 0, stream>>>(e_rows, counts);
    k_scan1<<<SCAN_NBLK, SCAN_CHUNK, 0, stream>>>(counts, rp, blockSums);
    k_scan2<<<1, 128, 0, stream>>>(blockSums);
    k_scan3<<<SCAN_NBLK, SCAN_CHUNK, 0, stream>>>(rp, blockSums, counts);
    k_scatter_edges<<<1024, 256, 0, stream>>>(e_rows, e_cols, rec_w, counts, csr);

    int*   rp_a   = rp;
    int2*  csr_a  = csr;
    float* bin_a  = b_in;
    float* yb_a   = ybufs;
    int*   arr_a  = arr;
    int*   cr_a   = convring;
    const int*   oidx_a = out_idx;
    const float* ow_a   = out_w;
    float* out_a  = out;
    void* args[] = { &rp_a, &csr_a, &bin_a, &yb_a, &arr_a, &cr_a,
                     &oidx_a, &ow_a, &out_a, &nbuf };
    void* kfn = sc1mode ? (void*)k_iterate<true> : (void*)k_iterate<false>;
    hipLaunchCooperativeKernel(kfn, dim3(NBLK), dim3(NT), args, 0, stream);
}